// Round 11
// baseline (4016.398 us; speedup 1.0000x reference)
//
#include <hip/hip_runtime.h>

typedef short bf16x8 __attribute__((ext_vector_type(8)));
typedef float f32x4 __attribute__((ext_vector_type(4)));
typedef unsigned u32x4 __attribute__((ext_vector_type(4)));

#define T_STEPS 1024
#define NBATCH  64
#define HID     1024
#define NIN     27
#define RINGN   32
#define LAG     8
#define BPG     16
#define NWG     256
#define SENT    0x7FC07FC0u

#define RING_DWORDS ((size_t)RINGN * NBATCH * HID / 2)    // 1,048,576
#define SLOT_DWORDS ((size_t)NBATCH * HID / 2)            // 32,768
#define WS_NEED     (RING_DWORDS * 4)                     // 4 MiB

__device__ __forceinline__ unsigned short f2bf(float f) {
    unsigned u = __float_as_uint(f);
    unsigned r = u + 0x7FFFu + ((u >> 16) & 1u);
    return (unsigned short)(r >> 16);
}
__device__ __forceinline__ float bf2f(unsigned short h) {
    return __uint_as_float(((unsigned)h) << 16);
}

// ---- system-coherent (cross-XCD) ops -- the R3-R5-proven primitives ----
__device__ __forceinline__ void ld_b128_sys(const void* p, u32x4& v) {
    asm volatile("global_load_dwordx4 %0, %1, off sc0 sc1" : "=v"(v) : "v"(p));
}
__device__ __forceinline__ void ld_b32_sys(const void* p, unsigned& v) {
    asm volatile("global_load_dword %0, %1, off sc0 sc1" : "=v"(v) : "v"(p));
}
__device__ __forceinline__ unsigned ld_poll_sys(const unsigned* p) {
    unsigned v;
    asm volatile("global_load_dword %0, %1, off sc0 sc1\n\ts_waitcnt vmcnt(0)"
                 : "=v"(v) : "v"(p) : "memory");
    return v;
}
__device__ __forceinline__ void st_b32_sys(void* p, unsigned v) {
    asm volatile("global_store_dword %0, %1, off sc0 sc1" :: "v"(p), "v"(v) : "memory");
}
__device__ __forceinline__ void wait_vm0() {
    asm volatile("s_waitcnt vmcnt(0)" ::: "memory");
    __builtin_amdgcn_sched_barrier(0);   // rule #18: pin consumers below the wait
}

// Persistent GRU, flag-free data-poll sync: 4 groups x 64 WGs. Group gb owns
// batches [16gb,16gb+16); WG gs owns hidden cols [16gs,16gs+16). W_hh slice
// (48x1024 bf16) register-resident; h carried EXACT in fp32 per thread;
// single bf16 ring (doubles as y_hat history for the fused delayed decode).
// Sync: ring slots are sentinel-poisoned (NaN pattern) before reuse; consumers
// cheap-poll 1 dword/producer, then load + verify. No flags, ONE barrier/step.
__global__ __launch_bounds__(256, 1)
void gru_persist(const float* __restrict__ x,
                 const int* __restrict__ delays,
                 const float* __restrict__ W_ih,
                 const float* __restrict__ W_hh,
                 const float* __restrict__ b_ih,
                 const float* __restrict__ b_hh,
                 const float* __restrict__ W_dec,
                 float* __restrict__ out,
                 unsigned short* __restrict__ ring_hi)
{
    const int tid  = threadIdx.x;
    const int lane = tid & 63;
    const int kq   = tid >> 6;          // wave id = K-quarter (0..3)
    const int gb   = blockIdx.x >> 6;   // batch group (0..3)
    const int gs   = blockIdx.x & 63;   // j-slice (0..63)
    const int j0   = gs * 16;
    const int l15  = lane & 15;
    const int lhi  = lane >> 4;
    const int Bg   = gb * BPG;

    __shared__ f32x4 red[2][13 * 64];   // parity: 3 gates x 4 waves + i_n
    __shared__ float ylds[2][256];      // decode y quarter-row, parity
    __shared__ float bias_lds[64];

    // ---- persistent W_hh bf16 fragments: 3 gates x 8 K-chunks ----
    bf16x8 wHH[3][8];
    #pragma unroll
    for (int n = 0; n < 3; ++n) {
        const float* wrow = W_hh + (size_t)(n * HID + j0 + l15) * HID;
        #pragma unroll
        for (int c = 0; c < 8; ++c) {
            const float* wr = wrow + kq * 256 + c * 32 + lhi * 8;
            #pragma unroll
            for (int jj = 0; jj < 8; ++jj) wHH[n][c][jj] = (short)f2bf(wr[jj]);
        }
    }
    bf16x8 wXH[3];
    #pragma unroll
    for (int n = 0; n < 3; ++n) {
        const float* wrow = W_ih + (size_t)(n * HID + j0 + l15) * NIN;
        #pragma unroll
        for (int jj = 0; jj < 8; ++jj) {
            const int kk = lhi * 8 + jj;
            wXH[n][jj] = (kk < NIN) ? (short)f2bf(wrow[kk]) : (short)0;
        }
    }
    if (tid < 16) {
        bias_lds[tid]      = b_ih[j0 + tid] + b_hh[j0 + tid];               // r
        bias_lds[16 + tid] = b_ih[HID + j0 + tid] + b_hh[HID + j0 + tid];   // z
        bias_lds[32 + tid] = b_ih[2 * HID + j0 + tid];                      // n (x side)
        bias_lds[48 + tid] = b_hh[2 * HID + j0 + tid];                      // n (h side)
    }
    // ---- fused decode assignment ----
    const int bdec  = gb * BPG + (gs >> 2);
    const int qdec  = gs & 3;
    const int d_del = delays[bdec];
    const int odec  = tid & 31;
    const int jgd   = tid >> 5;
    float wd[32];
    #pragma unroll
    for (int jj = 0; jj < 32; ++jj)
        wd[jj] = (odec < NIN) ? W_dec[(size_t)odec * HID + qdec * 256 + jgd * 32 + jj] : 0.f;

    const int jl = l15;
    const int bl = kq * 4 + lhi;
    const int arow = Bg + l15;          // A-fragment row = batch-in-group
    const unsigned* ringdw = (const unsigned*)ring_hi;

    float hprev = 0.f;
    bool dead = false;

    __syncthreads();

    #pragma clang loop unroll(disable)
    for (int t = 0; t < T_STEPS + LAG; ++t) {
        const int t_dec  = t - LAG;
        const int slot_prev = (t + RINGN - 1) & (RINGN - 1);

        // ---- (A) decode y-row load: data >=7 steps old, certainly landed
        unsigned ydw = 0;
        if (t_dec >= 0 && tid < 128) {
            const int tau = (t_dec < d_del) ? t_dec : (t_dec - d_del);
            const unsigned* yrow = ringdw
                + ((size_t)((tau & (RINGN - 1)) * NBATCH + bdec)) * (HID / 2) + qdec * 128;
            ld_b32_sys(yrow + tid, ydw);
        }
        // ---- (B) x fragments + x-MFMAs (wave 0): independent of h
        f32x4 z4 = {0.f, 0.f, 0.f, 0.f};
        f32x4 acc0 = z4, acc1 = z4, acc2 = z4, acc2x = z4;
        if (t < T_STEPS && kq == 0) {
            const float* xr = x + ((size_t)arow * T_STEPS + t) * NIN;
            bf16x8 axH = {}, axL = {};
            #pragma unroll
            for (int jj = 0; jj < 8; ++jj) {
                const int kk = lhi * 8 + jj;
                if (kk < NIN) {
                    float f = xr[kk];
                    unsigned short hi = f2bf(f);
                    axH[jj] = (short)hi;
                    axL[jj] = (short)f2bf(f - bf2f(hi));
                }
            }
            acc0  = __builtin_amdgcn_mfma_f32_16x16x32_bf16(axH, wXH[0], acc0, 0, 0, 0);
            acc1  = __builtin_amdgcn_mfma_f32_16x16x32_bf16(axH, wXH[1], acc1, 0, 0, 0);
            acc2x = __builtin_amdgcn_mfma_f32_16x16x32_bf16(axH, wXH[2], acc2x, 0, 0, 0);
            acc0  = __builtin_amdgcn_mfma_f32_16x16x32_bf16(axL, wXH[0], acc0, 0, 0, 0);
            acc1  = __builtin_amdgcn_mfma_f32_16x16x32_bf16(axL, wXH[1], acc1, 0, 0, 0);
            acc2x = __builtin_amdgcn_mfma_f32_16x16x32_bf16(axL, wXH[2], acc2x, 0, 0, 0);
        }
        __builtin_amdgcn_sched_barrier(0);

        // ---- (C) cheap data-poll: 1 dword per producer (16 lanes x 1 line).
        // Producer gs'=16kq+lane writes cols [256kq+16*lane, +16); sample its
        // dword at row Bg+lane. Slot was sentinel-poisoned at step t-8.
        if (t < T_STEPS && !dead) {
            const unsigned* pollp = ringdw
                + ((size_t)(slot_prev * NBATCH + Bg + l15)) * (HID / 2)
                + kq * 128 + l15 * 8;
            int iter = 0;
            for (;;) {
                unsigned v = 0;
                if (lane < 16) v = ld_poll_sys(pollp);
                if (__all(v != SENT)) break;
                if (++iter > (1 << 17)) { dead = true; break; }
            }
        }
        wait_vm0();   // poll already drained; covers y/x stragglers + tail

        // ---- (D) full load + sentinel verify (catches straggler dwords)
        u32x4 rawH[8];
        if (t < T_STEPS) {
            const unsigned short* aH = ring_hi + ((size_t)(slot_prev * NBATCH + arow)) * HID
                                     + kq * 256 + lhi * 8;
            int vr = 0;
            for (;;) {
                #pragma unroll
                for (int c = 0; c < 8; ++c) ld_b128_sys(aH + c * 32, rawH[c]);
                wait_vm0();
                bool ok = true;
                #pragma unroll
                for (int c = 0; c < 8; ++c)
                    #pragma unroll
                    for (int d = 0; d < 4; ++d) ok &= (rawH[c][d] != SENT);
                if (__all(ok)) break;
                if (++vr > 1024) { dead = true; break; }
            }
            #pragma unroll
            for (int c = 0; c < 8; ++c) {       // W . h
                bf16x8 a = __builtin_bit_cast(bf16x8, rawH[c]);
                acc0 = __builtin_amdgcn_mfma_f32_16x16x32_bf16(a, wHH[0][c], acc0, 0, 0, 0);
                acc1 = __builtin_amdgcn_mfma_f32_16x16x32_bf16(a, wHH[1][c], acc1, 0, 0, 0);
                acc2 = __builtin_amdgcn_mfma_f32_16x16x32_bf16(a, wHH[2][c], acc2, 0, 0, 0);
            }
            red[t & 1][(0 * 4 + kq) * 64 + lane] = acc0;
            red[t & 1][(1 * 4 + kq) * 64 + lane] = acc1;
            red[t & 1][(2 * 4 + kq) * 64 + lane] = acc2;
            if (kq == 0) red[t & 1][12 * 64 + lane] = acc2x;
        }
        if (t_dec >= 0 && tid < 128) {
            ylds[t & 1][2 * tid]     = bf2f((unsigned short)(ydw & 0xFFFFu));
            ylds[t & 1][2 * tid + 1] = bf2f((unsigned short)(ydw >> 16));
        }
        __syncthreads();   // the ONLY barrier per step (red/ylds parity-buffered)

        if (t < T_STEPS) {
            // reduce 4 K-quarter partials; C layout: col=lane&15, row=(lane>>4)*4+reg
            const float* redf = (const float*)&red[t & 1][0];
            const int ridx = (jl + 16 * (bl >> 2)) * 4 + (bl & 3);
            float gr = 0.f, gz = 0.f, gh_n = 0.f;
            #pragma unroll
            for (int w = 0; w < 4; ++w) {
                gr   += redf[((0 * 4 + w) * 64) * 4 + ridx];
                gz   += redf[((1 * 4 + w) * 64) * 4 + ridx];
                gh_n += redf[((2 * 4 + w) * 64) * 4 + ridx];
            }
            const float i_n = redf[(12 * 64) * 4 + ridx];
            const float r  = 1.f / (1.f + __expf(-(gr + bias_lds[jl])));
            const float z  = 1.f / (1.f + __expf(-(gz + bias_lds[16 + jl])));
            const float nn = tanhf(i_n + bias_lds[32 + jl] + r * (gh_n + bias_lds[48 + jl]));
            const float hnew = (1.f - z) * nn + z * hprev;
            hprev = hnew;
            // pack adjacent-j pair into one dword (even lanes store), then
            // re-poison slot t+7 (holds age-25 data; decode max age 23, drift<=1)
            const unsigned short hih = f2bf(hnew);
            const unsigned nhi = __shfl_xor((unsigned)hih, 1);
            if ((l15 & 1) == 0) {
                const unsigned dhi = (unsigned)hih | (nhi << 16);
                const int bg = Bg + bl;
                const size_t dwoff = (size_t)bg * (HID / 2) + ((j0 + jl) >> 1);
                unsigned* ph = (unsigned*)ring_hi + (size_t)(t & (RINGN - 1)) * SLOT_DWORDS + dwoff;
                unsigned* pp = (unsigned*)ring_hi + (size_t)((t + 7) & (RINGN - 1)) * SLOT_DWORDS + dwoff;
                st_b32_sys(ph, dhi);
                st_b32_sys(pp, SENT);
            }
            // no drain, no flag: the data IS the signal (next poll's vmcnt(0)
            // orders the poison store for the same-address reuse hazard)
        }
        // ---- decode MACs + atomics (shadow; other WGs are polling)
        if (t_dec >= 0) {
            float pdec = 0.f;
            if (odec < NIN) {
                const float* yrow = ylds[t & 1] + jgd * 32;
                #pragma unroll
                for (int k = 0; k < 32; ++k) pdec += yrow[k] * wd[k];
            }
            pdec += __shfl_xor(pdec, 32);   // fold the wave's two j-groups
            if (lane < 32 && odec < NIN)
                atomicAdd(out + ((size_t)bdec * T_STEPS + t_dec) * NIN + odec, pdec);
        }
    }
}

// poison slots 0..30 with the sentinel, zero slot 31 (= h(-1)); re-run every
// launch/replay so stale end-of-run ring contents can never read as valid.
__global__ void fill_ring_kernel(unsigned* __restrict__ ring)
{
    const size_t i = (size_t)blockIdx.x * blockDim.x + threadIdx.x;
    if (i < RING_DWORDS)
        ring[i] = (i >= (RINGN - 1) * SLOT_DWORDS) ? 0u : SENT;
}

__global__ void fill_out_kernel(float* __restrict__ out, const float* __restrict__ b_dec, int n)
{
    int idx = blockIdx.x * blockDim.x + threadIdx.x;
    if (idx < n) out[idx] = b_dec[idx % NIN];
}

extern "C" void kernel_launch(void* const* d_in, const int* in_sizes, int n_in,
                              void* d_out, int out_size, void* d_ws, size_t ws_size,
                              hipStream_t stream)
{
    (void)in_sizes; (void)n_in;
    const float* xx    = (const float*)d_in[0];
    const int*   dl    = (const int*)d_in[1];
    const float* W_ih  = (const float*)d_in[2];
    const float* W_hh  = (const float*)d_in[3];
    const float* b_ih  = (const float*)d_in[4];
    const float* b_hh  = (const float*)d_in[5];
    const float* W_dec = (const float*)d_in[6];
    const float* b_dec = (const float*)d_in[7];
    float* out = (float*)d_out;

    if (ws_size < WS_NEED) return;

    unsigned short* ring_hi = (unsigned short*)d_ws;

    fill_ring_kernel<<<dim3((unsigned)((RING_DWORDS + 255) / 256)), dim3(256), 0, stream>>>(
        (unsigned*)d_ws);
    fill_out_kernel<<<dim3((out_size + 255) / 256), dim3(256), 0, stream>>>(out, b_dec, out_size);

    void* args[] = {(void*)&xx, (void*)&dl, (void*)&W_ih, (void*)&W_hh, (void*)&b_ih,
                    (void*)&b_hh, (void*)&W_dec, (void*)&out, (void*)&ring_hi};
    hipError_t e = hipLaunchCooperativeKernel((void*)gru_persist, dim3(NWG), dim3(256),
                                              args, 0, stream);
    if (e != hipSuccess) {
        gru_persist<<<dim3(NWG), dim3(256), 0, stream>>>(xx, dl, W_ih, W_hh, b_ih, b_hh,
                                                         W_dec, out, ring_hi);
    }
}